// Round 6
// baseline (1783.508 us; speedup 1.0000x reference)
//
#include <hip/hip_runtime.h>
#include <math.h>

#define B_ROWS 32768
#define K_CODES 4096
#define D_DIM 128
#define MARGIN 1.5e-3f
#define CAP 48

typedef short bf16x8 __attribute__((ext_vector_type(8)));
typedef float f32x4 __attribute__((ext_vector_type(4)));

// RNE float->bf16 (finite inputs only)
__device__ __forceinline__ unsigned short f2bf(float f) {
  union { float f; unsigned int u; } v; v.f = f;
  unsigned int r = (v.u + 0x7FFFu + ((v.u >> 16) & 1u)) >> 16;
  return (unsigned short)r;
}

// order-preserving float<->uint mapping (for LDS atomicMin on scores)
__device__ __forceinline__ unsigned fmap(float f) {
  unsigned u = __float_as_uint(f);
  return (u & 0x80000000u) ? ~u : (u | 0x80000000u);
}
__device__ __forceinline__ float funmap(unsigned k) {
  unsigned u = (k & 0x80000000u) ? (k ^ 0x80000000u) : ~k;
  return __uint_as_float(u);
}

// ---------------------------------------------------------------------------
// Kernel 1: prep — x2/e2 (numpy pairwise order, validated) + eb bf16 cast.
// ---------------------------------------------------------------------------
__global__ __launch_bounds__(256) void prep(const float* __restrict__ x,
                                            const float* __restrict__ emb,
                                            float* __restrict__ x2,
                                            float* __restrict__ e2,
                                            unsigned short* __restrict__ ebb) {
  const int t0 = blockIdx.x * 256 + threadIdx.x;
  const int stride = gridDim.x * 256;
  for (int s = t0; s < B_ROWS * 8; s += stride) {
    int row = s >> 3, lane = s & 7;
    const float* src = x + (size_t)row * D_DIM;
    float v = src[lane];
    float t = v * v;
    asm volatile("" : "+v"(t));  // keep fl(v*v) un-fused
    float acc = t;
#pragma unroll
    for (int i = 1; i < 16; ++i) {
      float w = src[i * 8 + lane];
      float tt = w * w;
      asm volatile("" : "+v"(tt));
      acc = acc + tt;
    }
    acc = acc + __shfl_xor(acc, 1, 64);
    acc = acc + __shfl_xor(acc, 2, 64);
    acc = acc + __shfl_xor(acc, 4, 64);
    if (lane == 0) x2[row] = acc;
  }
  for (int s = t0; s < K_CODES * 8; s += stride) {
    int row = s >> 3, lane = s & 7;
    const float* src = emb + (size_t)row * D_DIM;
    float v = src[lane];
    float t = v * v;
    asm volatile("" : "+v"(t));
    float acc = t;
#pragma unroll
    for (int i = 1; i < 16; ++i) {
      float w = src[i * 8 + lane];
      float tt = w * w;
      asm volatile("" : "+v"(tt));
      acc = acc + tt;
    }
    acc = acc + __shfl_xor(acc, 1, 64);
    acc = acc + __shfl_xor(acc, 2, 64);
    acc = acc + __shfl_xor(acc, 4, 64);
    if (lane == 0) e2[row] = acc;
  }
  for (int g = t0; g < K_CODES * D_DIM / 8; g += stride) {
    float4 a = ((const float4*)emb)[g * 2];
    float4 b = ((const float4*)emb)[g * 2 + 1];
    ushort4 o0 = make_ushort4(f2bf(a.x), f2bf(a.y), f2bf(a.z), f2bf(a.w));
    ushort4 o1 = make_ushort4(f2bf(b.x), f2bf(b.y), f2bf(b.z), f2bf(b.w));
    ((ushort4*)ebb)[g * 2] = o0;
    ((ushort4*)ebb)[g * 2 + 1] = o1;
  }
}

// ---------------------------------------------------------------------------
// Kernel 2: SINGLE-PASS MFMA argmin + exact rescore + gather/losses.
// 512 threads (8 waves), 64 rows/block, 512 blocks -> 16 waves/CU (4/SIMD).
// Wave w covers n-tile w of each 128-code chunk (1 n-tile, 4 m-tiles).
// af[4][4] (A-fragments, bf16 of x) hoisted in 64 VGPRs for whole kernel.
// Chunk 0 calibrates a per-row bound (cross-lane+cross-wave min + MARGIN,
// one barrier).  Chunks 1..31 stream: MFMA, t~ = fmaf(-2,acc,e2); append
// (col,t~) when t~ <= rm+MARGIN; rm = fmin(rm,t~); every 4 chunks rm is
// shfl-reduced and merged into LDS RMM via atomicMin (order-preserving uint).
// Bound >= final_min+MARGIN always -> collected set is a superset of all
// possible exact winners (2E<=M bound validated rounds 4-5).  End: filter by
// exact final min, exact fp32 rescore (validated ascending-d fmaf chain),
// (s,col) lexicographic min -> bit-exact first-index tie-break.
// ---------------------------------------------------------------------------
__global__ __launch_bounds__(512, 4) void vq_main(
    const float* __restrict__ x, const float* __restrict__ emb,
    const unsigned short* __restrict__ eb,
    const float* __restrict__ x2g, const float* __restrict__ e2g,
    float* __restrict__ out_q, float* __restrict__ out_idx,
    unsigned int* __restrict__ counts, double* __restrict__ sums) {
  __shared__ float m2[64 * 8];
  __shared__ unsigned RMM[64];
  __shared__ unsigned cnt[64];
  __shared__ unsigned short colsL[64 * CAP];
  __shared__ float tvalsL[64 * CAP];
  __shared__ int bidxs[64];
  __shared__ double lred[16];
  __shared__ float redv[512];
  __shared__ int redi[512];

  const int tid = threadIdx.x;
  const int wid = tid >> 6;        // 0..7 -> n-tile wid
  const int lane = tid & 63;
  const int q = lane >> 4, lr = lane & 15;
  const int rowbase = blockIdx.x * 64;

  // ---- hoist A fragments: af[mi][ks] = bf16(x[rowbase+mi*16+lr][ks*32+q*8..]) ----
  bf16x8 af[4][4];
#pragma unroll
  for (int mi = 0; mi < 4; ++mi) {
    const float* xr = x + (size_t)(rowbase + mi * 16 + lr) * D_DIM;
#pragma unroll
    for (int ks = 0; ks < 4; ++ks) {
      float4 v0 = *(const float4*)(xr + ks * 32 + q * 8);
      float4 v1 = *(const float4*)(xr + ks * 32 + q * 8 + 4);
      bf16x8 f;
      f[0] = (short)f2bf(v0.x); f[1] = (short)f2bf(v0.y);
      f[2] = (short)f2bf(v0.z); f[3] = (short)f2bf(v0.w);
      f[4] = (short)f2bf(v1.x); f[5] = (short)f2bf(v1.y);
      f[6] = (short)f2bf(v1.z); f[7] = (short)f2bf(v1.w);
      af[mi][ks] = f;
    }
  }
  if (tid < 64) cnt[tid] = 0;

  // ---- calibration on chunk 0 ----
  float tt[16];
  {
    const unsigned short* er0 = eb + (size_t)(wid * 16 + lr) * D_DIM;
    bf16x8 bf0[4];
#pragma unroll
    for (int ks = 0; ks < 4; ++ks) bf0[ks] = *(const bf16x8*)(er0 + ks * 32 + q * 8);
    float e0 = e2g[wid * 16 + lr];
    f32x4 acc[4];
#pragma unroll
    for (int mi = 0; mi < 4; ++mi) { f32x4 z = {0.f, 0.f, 0.f, 0.f}; acc[mi] = z; }
#pragma unroll
    for (int ks = 0; ks < 4; ++ks)
#pragma unroll
      for (int mi = 0; mi < 4; ++mi)
        acc[mi] = __builtin_amdgcn_mfma_f32_16x16x32_bf16(af[mi][ks], bf0[ks],
                                                          acc[mi], 0, 0, 0);
#pragma unroll
    for (int mi = 0; mi < 4; ++mi)
#pragma unroll
      for (int rg = 0; rg < 4; ++rg)
        tt[mi * 4 + rg] = __builtin_fmaf(-2.0f, acc[mi][rg], e0);
    // cross-lane (lr) min, write per-wave slice
#pragma unroll
    for (int sl = 0; sl < 16; ++sl) {
      float v = tt[sl];
      v = fminf(v, __shfl_xor(v, 1, 64));
      v = fminf(v, __shfl_xor(v, 2, 64));
      v = fminf(v, __shfl_xor(v, 4, 64));
      v = fminf(v, __shfl_xor(v, 8, 64));
      if (lr == 0) m2[((sl >> 2) * 16 + q * 4 + (sl & 3)) * 8 + wid] = v;
    }
  }
  __syncthreads();
  if (tid < 64) {
    float v = m2[tid * 8];
#pragma unroll
    for (int w = 1; w < 8; ++w) v = fminf(v, m2[tid * 8 + w]);
    RMM[tid] = fmap(v);
  }
  __syncthreads();

  // ---- load per-thread running-min regs from RMM; append chunk-0 survivors ----
  float rm[16];
#pragma unroll
  for (int mi = 0; mi < 4; ++mi) {
    uint4 rr = *(const uint4*)&RMM[mi * 16 + q * 4];
    rm[mi * 4 + 0] = funmap(rr.x);
    rm[mi * 4 + 1] = funmap(rr.y);
    rm[mi * 4 + 2] = funmap(rr.z);
    rm[mi * 4 + 3] = funmap(rr.w);
  }
  {
    int col0 = wid * 16 + lr;
#pragma unroll
    for (int sl = 0; sl < 16; ++sl) {
      if (tt[sl] <= rm[sl] + MARGIN) {
        int row = (sl >> 2) * 16 + q * 4 + (sl & 3);
        unsigned p = atomicAdd(&cnt[row], 1u);
        if (p < CAP) { colsL[row * CAP + p] = (unsigned short)col0; tvalsL[row * CAP + p] = tt[sl]; }
      }
    }
  }

  // ---- stream chunks 1..31 ----
#pragma unroll 1
  for (int ch = 1; ch < 32; ++ch) {
    const unsigned short* er = eb + ((size_t)(ch * 128 + wid * 16 + lr)) * D_DIM;
    bf16x8 bf[4];
#pragma unroll
    for (int ks = 0; ks < 4; ++ks) bf[ks] = *(const bf16x8*)(er + ks * 32 + q * 8);
    float ev = e2g[ch * 128 + wid * 16 + lr];
    f32x4 acc[4];
#pragma unroll
    for (int mi = 0; mi < 4; ++mi) { f32x4 z = {0.f, 0.f, 0.f, 0.f}; acc[mi] = z; }
#pragma unroll
    for (int ks = 0; ks < 4; ++ks)
#pragma unroll
      for (int mi = 0; mi < 4; ++mi)
        acc[mi] = __builtin_amdgcn_mfma_f32_16x16x32_bf16(af[mi][ks], bf[ks],
                                                          acc[mi], 0, 0, 0);
    int colc = ch * 128 + wid * 16 + lr;
#pragma unroll
    for (int mi = 0; mi < 4; ++mi)
#pragma unroll
      for (int rg = 0; rg < 4; ++rg) {
        float t = __builtin_fmaf(-2.0f, acc[mi][rg], ev);
        int sl = mi * 4 + rg;
        if (t <= rm[sl] + MARGIN) {
          int row = mi * 16 + q * 4 + rg;
          unsigned p = atomicAdd(&cnt[row], 1u);
          if (p < CAP) { colsL[row * CAP + p] = (unsigned short)colc; tvalsL[row * CAP + p] = t; }
        }
        rm[sl] = fminf(rm[sl], t);
      }
    if ((ch & 3) == 3) {  // refresh shared bound (incl. final ch=31)
#pragma unroll
      for (int sl = 0; sl < 16; ++sl) {
        float v = rm[sl];
        v = fminf(v, __shfl_xor(v, 1, 64));
        v = fminf(v, __shfl_xor(v, 2, 64));
        v = fminf(v, __shfl_xor(v, 4, 64));
        v = fminf(v, __shfl_xor(v, 8, 64));
        rm[sl] = v;
      }
      if (lr == 0) {
#pragma unroll
        for (int mi = 0; mi < 4; ++mi)
#pragma unroll
          for (int rg = 0; rg < 4; ++rg)
            atomicMin(&RMM[mi * 16 + q * 4 + rg], fmap(rm[mi * 4 + rg]));
      }
#pragma unroll
      for (int mi = 0; mi < 4; ++mi) {
        uint4 rr = *(const uint4*)&RMM[mi * 16 + q * 4];
        rm[mi * 4 + 0] = fminf(rm[mi * 4 + 0], funmap(rr.x));
        rm[mi * 4 + 1] = fminf(rm[mi * 4 + 1], funmap(rr.y));
        rm[mi * 4 + 2] = fminf(rm[mi * 4 + 2], funmap(rr.z));
        rm[mi * 4 + 3] = fminf(rm[mi * 4 + 3], funmap(rr.w));
      }
    }
  }
  __syncthreads();  // lists, cnt, RMM final

  // ---- exact rescore of filtered candidates (tid<64, one row each) ----
  if (tid < 64 && cnt[tid] <= CAP) {
    int c = (int)cnt[tid];
    float mlim = funmap(RMM[tid]) + MARGIN;  // exact global bf16-min + M
    float xs2 = x2g[rowbase + tid];
    const float* xr = x + (size_t)(rowbase + tid) * D_DIM;
    float best = 3.4e38f;
    int bidx = 0x7fffffff;
    for (int j = 0; j < c; ++j) {
      if (tvalsL[tid * CAP + j] > mlim) continue;
      int col = colsL[tid * CAP + j];
      float dot = 0.f;
      const float4* ev = (const float4*)(emb + (size_t)col * D_DIM);
#pragma unroll 8
      for (int d4 = 0; d4 < 32; ++d4) {  // exact ascending-d fmaf chain
        float4 e4 = ev[d4];
        dot = __builtin_fmaf(xr[d4 * 4 + 0], e4.x, dot);
        dot = __builtin_fmaf(xr[d4 * 4 + 1], e4.y, dot);
        dot = __builtin_fmaf(xr[d4 * 4 + 2], e4.z, dot);
        dot = __builtin_fmaf(xr[d4 * 4 + 3], e4.w, dot);
      }
      float t1 = xs2 + e2g[col];                 // fl(x2+e2)
      float s = __builtin_fmaf(-2.0f, dot, t1);  // fl(t1 - 2*dot)
      if (s < best || (s == best && col < bidx)) { best = s; bidx = col; }
    }
    out_idx[rowbase + tid] = (float)bidx;
    bidxs[tid] = bidx;
    atomicAdd(&counts[bidx], 1u);
  }
  __syncthreads();

  // ---- overflow fallback: exact full scan (expected never) ----
  for (int r = 0; r < 64; ++r) {
    if (cnt[r] <= CAP) continue;
    float xs2 = x2g[rowbase + r];
    const float* xr = x + (size_t)(rowbase + r) * D_DIM;
    float lbest = 3.4e38f;
    int lidx = 0x7fffffff;
    for (int c0 = tid; c0 < K_CODES; c0 += 512) {
      float dot = 0.f;
      const float4* ev = (const float4*)(emb + (size_t)c0 * D_DIM);
      for (int d4 = 0; d4 < 32; ++d4) {
        float4 e4 = ev[d4];
        dot = __builtin_fmaf(xr[d4 * 4 + 0], e4.x, dot);
        dot = __builtin_fmaf(xr[d4 * 4 + 1], e4.y, dot);
        dot = __builtin_fmaf(xr[d4 * 4 + 2], e4.z, dot);
        dot = __builtin_fmaf(xr[d4 * 4 + 3], e4.w, dot);
      }
      float s = __builtin_fmaf(-2.0f, dot, xs2 + e2g[c0]);
      if (s < lbest || (s == lbest && c0 < lidx)) { lbest = s; lidx = c0; }
    }
    redv[tid] = lbest;
    redi[tid] = lidx;
    __syncthreads();
    if (tid == 0) {
      float bv = redv[0]; int bi = redi[0];
      for (int t = 1; t < 512; ++t) {
        float v = redv[t]; int i2 = redi[t];
        if (v < bv || (v == bv && i2 < bi)) { bv = v; bi = i2; }
      }
      out_idx[rowbase + r] = (float)bi;
      bidxs[r] = bi;
      atomicAdd(&counts[bi], 1u);
    }
    __syncthreads();
  }
  __syncthreads();  // bidxs ready

  // ---- fused gather + straight-through + losses (validated math) ----
  {
    int gr = tid >> 3, seg = tid & 7;   // 8 threads/row, 16 floats each
    int gidx = bidxs[gr];
    const float4* ev = (const float4*)(emb + (size_t)gidx * D_DIM + seg * 16);
    const float4* xv4 = (const float4*)(x + (size_t)(rowbase + gr) * D_DIM + seg * 16);
    float4* oq = (float4*)(out_q + (size_t)(rowbase + gr) * D_DIM + seg * 16);
    double es = 0.0, qs = 0.0;
#pragma unroll
    for (int j = 0; j < 4; ++j) {
      float4 e4 = ev[j];
      float4 xv = xv4[j];
      float d0 = e4.x - xv.x, d1 = e4.y - xv.y, d2 = e4.z - xv.z, d3 = e4.w - xv.w;
      float s0 = xv.x + d0, s1 = xv.y + d1, s2 = xv.z + d2, s3 = xv.w + d3;
      oq[j] = make_float4(s0, s1, s2, s3);
      float g0 = s0 - xv.x, g1 = s1 - xv.y, g2 = s2 - xv.z, g3 = s3 - xv.w;
      es += (double)(d0 * d0) + (double)(d1 * d1) + (double)(d2 * d2) + (double)(d3 * d3);
      qs += (double)(g0 * g0) + (double)(g1 * g1) + (double)(g2 * g2) + (double)(g3 * g3);
    }
#pragma unroll
    for (int off = 32; off >= 1; off >>= 1) {
      es += __shfl_down(es, off, 64);
      qs += __shfl_down(qs, off, 64);
    }
    if (lane == 0) { lred[wid * 2] = es; lred[wid * 2 + 1] = qs; }
    __syncthreads();
    if (tid == 0) {
      double e = 0.0, qq = 0.0;
#pragma unroll
      for (int w = 0; w < 8; ++w) { e += lred[w * 2]; qq += lred[w * 2 + 1]; }
      atomicAdd(&sums[0], e);
      atomicAdd(&sums[1], qq);
    }
  }
}

// ---------------------------------------------------------------------------
// Kernel 3 (validated): finalize scalars.
// ---------------------------------------------------------------------------
__global__ __launch_bounds__(256) void vq_final(const unsigned int* __restrict__ counts,
                                                const double* __restrict__ sums,
                                                float* __restrict__ out_scalars) {
  double s = 0.0;
  for (int k = threadIdx.x; k < K_CODES; k += 256) {
    float p = (float)counts[k] * (1.0f / 32768.0f);
    float term = p * logf(p + 1e-10f);
    s += (double)term;
  }
#pragma unroll
  for (int off = 32; off >= 1; off >>= 1) s += __shfl_down(s, off, 64);
  __shared__ double red[4];
  if ((threadIdx.x & 63) == 0) red[threadIdx.x >> 6] = s;
  __syncthreads();
  if (threadIdx.x == 0) {
    double tot = red[0] + red[1] + red[2] + red[3];
    float e_lat = (float)(sums[0] / (double)(B_ROWS * D_DIM));
    float q_lat = (float)(sums[1] / (double)(B_ROWS * D_DIM));
    float vq = q_lat + 0.25f * e_lat;   // fl(q + fl(0.25*e)); 0.25*e exact
    out_scalars[0] = vq;
    out_scalars[1] = e_lat;
    out_scalars[2] = q_lat;
    out_scalars[3] = expf(-(float)tot);
  }
}

extern "C" void kernel_launch(void* const* d_in, const int* in_sizes, int n_in,
                              void* d_out, int out_size, void* d_ws, size_t ws_size,
                              hipStream_t stream) {
  const float* x = (const float*)d_in[0];
  const float* emb = (const float*)d_in[1];
  float* out = (float*)d_out;

  // ws: counts[4096]u32 @0 | sums[2]f64 @16384 | x2[32768] @16400 |
  //     e2[4096] @147472 | eb[4096*128]u16 @163856   (~1.21 MB total)
  unsigned int* counts = (unsigned int*)d_ws;
  double* sums = (double*)((char*)d_ws + 16384);
  float* x2 = (float*)((char*)d_ws + 16400);
  float* e2 = (float*)((char*)d_ws + 147472);
  unsigned short* eb = (unsigned short*)((char*)d_ws + 163856);

  float* out_idx = out + (size_t)B_ROWS * D_DIM;
  float* out_scalars = out_idx + B_ROWS;

  hipMemsetAsync(d_ws, 0, 16400, stream);  // zero counts + sums
  prep<<<512, 256, 0, stream>>>(x, emb, x2, e2, eb);
  vq_main<<<B_ROWS / 64, 512, 0, stream>>>(x, emb, eb, x2, e2, out, out_idx,
                                           counts, sums);
  vq_final<<<1, 256, 0, stream>>>(counts, sums, out_scalars);
}

// Round 7
// 531.974 us; speedup vs baseline: 3.3526x; 3.3526x over previous
//
#include <hip/hip_runtime.h>
#include <math.h>

#define B_ROWS 32768
#define K_CODES 4096
#define D_DIM 128
#define MARGIN 1.5e-3f
#define CAP 24

typedef short bf16x8 __attribute__((ext_vector_type(8)));
typedef float f32x4 __attribute__((ext_vector_type(4)));

// RNE float->bf16 (finite inputs only)
__device__ __forceinline__ unsigned short f2bf(float f) {
  union { float f; unsigned int u; } v; v.f = f;
  unsigned int r = (v.u + 0x7FFFu + ((v.u >> 16) & 1u)) >> 16;
  return (unsigned short)r;
}

// order-preserving float<->uint mapping
__device__ __forceinline__ unsigned fmap(float f) {
  unsigned u = __float_as_uint(f);
  return (u & 0x80000000u) ? ~u : (u | 0x80000000u);
}
__device__ __forceinline__ float funmap(unsigned k) {
  unsigned u = (k & 0x80000000u) ? (k ^ 0x80000000u) : ~k;
  return __uint_as_float(u);
}

// ---------------------------------------------------------------------------
// Kernel 1: prep — e2 (validated numpy pairwise order) + eb cast packed in
// MFMA-fragment order: eb[((ch*8+nt)*4+ks)*64 + lane]*8 shorts, so a wave's
// B-fragment load is one fully-coalesced lane-contiguous dwordx4 (1 KB/instr).
// ---------------------------------------------------------------------------
__global__ __launch_bounds__(256) void prep(const float* __restrict__ emb,
                                            float* __restrict__ e2,
                                            unsigned short* __restrict__ eb) {
  const int t0 = blockIdx.x * 256 + threadIdx.x;
  const int stride = gridDim.x * 256;
  // (a) e2: 8 lanes/row, accumulator j sums fl(e_{8i+j}^2) i ascending, then
  // shfl-xor 1,2,4 == ((r0+r1)+(r2+r3))+((r4+r5)+(r6+r7)).
  for (int s = t0; s < K_CODES * 8; s += stride) {
    int row = s >> 3, lane = s & 7;
    const float* src = emb + (size_t)row * D_DIM;
    float v = src[lane];
    float t = v * v;
    asm volatile("" : "+v"(t));  // keep fl(v*v) un-fused
    float acc = t;
#pragma unroll
    for (int i = 1; i < 16; ++i) {
      float w = src[i * 8 + lane];
      float tt = w * w;
      asm volatile("" : "+v"(tt));
      acc = acc + tt;
    }
    acc = acc + __shfl_xor(acc, 1, 64);
    acc = acc + __shfl_xor(acc, 2, 64);
    acc = acc + __shfl_xor(acc, 4, 64);
    if (lane == 0) e2[row] = acc;
  }
  // (b) packed bf16 cast: work item = (code c, ks)
  for (int g = t0; g < K_CODES * 4; g += stride) {
    int c = g >> 2, ks = g & 3;
    int ch = c >> 7, nt = (c >> 4) & 7, lr = c & 15;
    const float4* src = (const float4*)(emb + (size_t)c * D_DIM + ks * 32);
    unsigned short* dst = eb + ((size_t)((ch * 8 + nt) * 4 + ks) * 64 + lr) * 8;
#pragma unroll
    for (int qq = 0; qq < 4; ++qq) {
      float4 v0 = src[qq * 2];
      float4 v1 = src[qq * 2 + 1];
      ushort4 o0 = make_ushort4(f2bf(v0.x), f2bf(v0.y), f2bf(v0.z), f2bf(v0.w));
      ushort4 o1 = make_ushort4(f2bf(v1.x), f2bf(v1.y), f2bf(v1.z), f2bf(v1.w));
      *(ushort4*)(dst + qq * 128) = o0;
      *(ushort4*)(dst + qq * 128 + 4) = o1;
    }
  }
}

// ---------------------------------------------------------------------------
// Kernel 2: minpass — pure MFMA bf16 min.  256 thr (4 waves), 32 rows/block,
// 1024 blocks.  Wave wid covers n-tiles wid*2, wid*2+1; all waves cover
// m-tiles 0..1 (af[2][4] = 32 VGPRs).  Rows are block-exclusive -> plain
// store of fmap(min) to RMMg.  launch_bounds(256,4): demand ~105 regs.
// ---------------------------------------------------------------------------
__global__ __launch_bounds__(256, 4) void minpass(
    const float* __restrict__ x, const unsigned short* __restrict__ eb,
    const float* __restrict__ e2g, unsigned int* __restrict__ RMMg) {
  __shared__ float m2[32 * 4];
  const int tid = threadIdx.x;
  const int wid = tid >> 6, lane = tid & 63;
  const int q = lane >> 4, lr = lane & 15;
  const int rowbase = blockIdx.x * 32;

  bf16x8 af[2][4];
#pragma unroll
  for (int mi = 0; mi < 2; ++mi) {
    const float* xr = x + (size_t)(rowbase + mi * 16 + lr) * D_DIM;
#pragma unroll
    for (int ks = 0; ks < 4; ++ks) {
      float4 v0 = *(const float4*)(xr + ks * 32 + q * 8);
      float4 v1 = *(const float4*)(xr + ks * 32 + q * 8 + 4);
      bf16x8 f;
      f[0] = (short)f2bf(v0.x); f[1] = (short)f2bf(v0.y);
      f[2] = (short)f2bf(v0.z); f[3] = (short)f2bf(v0.w);
      f[4] = (short)f2bf(v1.x); f[5] = (short)f2bf(v1.y);
      f[6] = (short)f2bf(v1.z); f[7] = (short)f2bf(v1.w);
      af[mi][ks] = f;
    }
  }

  float rm[8];
#pragma unroll
  for (int sl = 0; sl < 8; ++sl) rm[sl] = 3.4e38f;

#pragma unroll 2
  for (int ch = 0; ch < 32; ++ch) {
    bf16x8 bf[2][4];
    float ev[2];
#pragma unroll
    for (int ni = 0; ni < 2; ++ni) {
      int nt = wid * 2 + ni;
#pragma unroll
      for (int ks = 0; ks < 4; ++ks)
        bf[ni][ks] = *(const bf16x8*)(eb + ((size_t)((ch * 8 + nt) * 4 + ks) * 64 + lane) * 8);
      ev[ni] = e2g[ch * 128 + nt * 16 + lr];
    }
    f32x4 acc[2][2];
#pragma unroll
    for (int mi = 0; mi < 2; ++mi)
#pragma unroll
      for (int ni = 0; ni < 2; ++ni) { f32x4 z = {0.f, 0.f, 0.f, 0.f}; acc[mi][ni] = z; }
#pragma unroll
    for (int ks = 0; ks < 4; ++ks)
#pragma unroll
      for (int mi = 0; mi < 2; ++mi)
#pragma unroll
        for (int ni = 0; ni < 2; ++ni)
          acc[mi][ni] = __builtin_amdgcn_mfma_f32_16x16x32_bf16(
              af[mi][ks], bf[ni][ks], acc[mi][ni], 0, 0, 0);
#pragma unroll
    for (int mi = 0; mi < 2; ++mi)
#pragma unroll
      for (int ni = 0; ni < 2; ++ni)
#pragma unroll
        for (int rg = 0; rg < 4; ++rg) {
          float t = __builtin_fmaf(-2.0f, acc[mi][ni][rg], ev[ni]);
          rm[mi * 4 + rg] = fminf(rm[mi * 4 + rg], t);
        }
  }

#pragma unroll
  for (int sl = 0; sl < 8; ++sl) {
    float v = rm[sl];
    v = fminf(v, __shfl_xor(v, 1, 64));
    v = fminf(v, __shfl_xor(v, 2, 64));
    v = fminf(v, __shfl_xor(v, 4, 64));
    v = fminf(v, __shfl_xor(v, 8, 64));
    if (lr == 0) m2[((sl >> 2) * 16 + q * 4 + (sl & 3)) * 4 + wid] = v;
  }
  __syncthreads();
  if (tid < 32) {
    float a = fminf(m2[tid * 4], m2[tid * 4 + 1]);
    float b = fminf(m2[tid * 4 + 2], m2[tid * 4 + 3]);
    RMMg[rowbase + tid] = fmap(fminf(a, b));  // row is block-exclusive
  }
}

// ---------------------------------------------------------------------------
// Kernel 3: collect — recompute bf16 scores, append cols with t <= min+M.
// Same layout as minpass.  Tight bound (exact global bf16 min) -> ~6/row.
// LDS cnt/lists, flushed to global (rows block-exclusive, plain stores).
// ---------------------------------------------------------------------------
__global__ __launch_bounds__(256, 4) void collect(
    const float* __restrict__ x, const unsigned short* __restrict__ eb,
    const float* __restrict__ e2g, const unsigned int* __restrict__ RMMg,
    unsigned int* __restrict__ cntg, unsigned short* __restrict__ listsg) {
  __shared__ float mlim[32];
  __shared__ unsigned cnt[32];
  __shared__ unsigned short lists[32 * CAP];
  const int tid = threadIdx.x;
  const int wid = tid >> 6, lane = tid & 63;
  const int q = lane >> 4, lr = lane & 15;
  const int rowbase = blockIdx.x * 32;

  if (tid < 32) {
    mlim[tid] = funmap(RMMg[rowbase + tid]) + MARGIN;
    cnt[tid] = 0;
  }

  bf16x8 af[2][4];
#pragma unroll
  for (int mi = 0; mi < 2; ++mi) {
    const float* xr = x + (size_t)(rowbase + mi * 16 + lr) * D_DIM;
#pragma unroll
    for (int ks = 0; ks < 4; ++ks) {
      float4 v0 = *(const float4*)(xr + ks * 32 + q * 8);
      float4 v1 = *(const float4*)(xr + ks * 32 + q * 8 + 4);
      bf16x8 f;
      f[0] = (short)f2bf(v0.x); f[1] = (short)f2bf(v0.y);
      f[2] = (short)f2bf(v0.z); f[3] = (short)f2bf(v0.w);
      f[4] = (short)f2bf(v1.x); f[5] = (short)f2bf(v1.y);
      f[6] = (short)f2bf(v1.z); f[7] = (short)f2bf(v1.w);
      af[mi][ks] = f;
    }
  }
  __syncthreads();
  float ml[8];
#pragma unroll
  for (int mi = 0; mi < 2; ++mi)
#pragma unroll
    for (int rg = 0; rg < 4; ++rg) ml[mi * 4 + rg] = mlim[mi * 16 + q * 4 + rg];

#pragma unroll 2
  for (int ch = 0; ch < 32; ++ch) {
    bf16x8 bf[2][4];
    float ev[2];
#pragma unroll
    for (int ni = 0; ni < 2; ++ni) {
      int nt = wid * 2 + ni;
#pragma unroll
      for (int ks = 0; ks < 4; ++ks)
        bf[ni][ks] = *(const bf16x8*)(eb + ((size_t)((ch * 8 + nt) * 4 + ks) * 64 + lane) * 8);
      ev[ni] = e2g[ch * 128 + nt * 16 + lr];
    }
    f32x4 acc[2][2];
#pragma unroll
    for (int mi = 0; mi < 2; ++mi)
#pragma unroll
      for (int ni = 0; ni < 2; ++ni) { f32x4 z = {0.f, 0.f, 0.f, 0.f}; acc[mi][ni] = z; }
#pragma unroll
    for (int ks = 0; ks < 4; ++ks)
#pragma unroll
      for (int mi = 0; mi < 2; ++mi)
#pragma unroll
        for (int ni = 0; ni < 2; ++ni)
          acc[mi][ni] = __builtin_amdgcn_mfma_f32_16x16x32_bf16(
              af[mi][ks], bf[ni][ks], acc[mi][ni], 0, 0, 0);
#pragma unroll
    for (int mi = 0; mi < 2; ++mi)
#pragma unroll
      for (int ni = 0; ni < 2; ++ni) {
        int colc = ch * 128 + (wid * 2 + ni) * 16 + lr;
#pragma unroll
        for (int rg = 0; rg < 4; ++rg) {
          float t = __builtin_fmaf(-2.0f, acc[mi][ni][rg], ev[ni]);
          if (t <= ml[mi * 4 + rg]) {
            int row = mi * 16 + q * 4 + rg;
            unsigned p = atomicAdd(&cnt[row], 1u);
            if (p < CAP) lists[row * CAP + p] = (unsigned short)colc;
          }
        }
      }
  }
  __syncthreads();
  if (tid < 32) cntg[rowbase + tid] = cnt[tid];
  for (int i = tid; i < 32 * CAP; i += 256)
    listsg[(size_t)rowbase * CAP + i] = lists[i];
}

// ---------------------------------------------------------------------------
// Kernel 4: rescore — exact fp32 (bit-validated chain) over candidates only.
// 256 blocks x 128 thr, one row/thread.  x2 computed in-thread with the exact
// numpy pairwise order (8 named accumulators + combine tree).  Overflow rows
// (cnt > CAP, expected never) handled block-cooperatively.
// ---------------------------------------------------------------------------
__global__ __launch_bounds__(128) void rescore(
    const float* __restrict__ x, const float* __restrict__ emb,
    const float* __restrict__ e2g, const unsigned int* __restrict__ cntg,
    const unsigned short* __restrict__ listsg, float* __restrict__ out_idx,
    unsigned int* __restrict__ counts) {
  __shared__ int nofl;
  __shared__ int oflrows[128];
  __shared__ float redv[128];
  __shared__ int redi[128];
  const int tid = threadIdx.x;
  const int r = blockIdx.x * 128 + tid;
  if (tid == 0) nofl = 0;
  __syncthreads();

  const float* xr = x + (size_t)r * D_DIM;
  // x2: numpy pairwise order, serial (bitwise == validated 8-lane version)
  float a0, a1, a2, a3, a4, a5, a6, a7;
  {
    float4 v0 = ((const float4*)xr)[0], v1 = ((const float4*)xr)[1];
    float t;
    t = v0.x * v0.x; asm volatile("" : "+v"(t)); a0 = t;
    t = v0.y * v0.y; asm volatile("" : "+v"(t)); a1 = t;
    t = v0.z * v0.z; asm volatile("" : "+v"(t)); a2 = t;
    t = v0.w * v0.w; asm volatile("" : "+v"(t)); a3 = t;
    t = v1.x * v1.x; asm volatile("" : "+v"(t)); a4 = t;
    t = v1.y * v1.y; asm volatile("" : "+v"(t)); a5 = t;
    t = v1.z * v1.z; asm volatile("" : "+v"(t)); a6 = t;
    t = v1.w * v1.w; asm volatile("" : "+v"(t)); a7 = t;
#pragma unroll
    for (int i = 1; i < 16; ++i) {
      float4 w0 = ((const float4*)xr)[i * 2], w1 = ((const float4*)xr)[i * 2 + 1];
      t = w0.x * w0.x; asm volatile("" : "+v"(t)); a0 = a0 + t;
      t = w0.y * w0.y; asm volatile("" : "+v"(t)); a1 = a1 + t;
      t = w0.z * w0.z; asm volatile("" : "+v"(t)); a2 = a2 + t;
      t = w0.w * w0.w; asm volatile("" : "+v"(t)); a3 = a3 + t;
      t = w1.x * w1.x; asm volatile("" : "+v"(t)); a4 = a4 + t;
      t = w1.y * w1.y; asm volatile("" : "+v"(t)); a5 = a5 + t;
      t = w1.z * w1.z; asm volatile("" : "+v"(t)); a6 = a6 + t;
      t = w1.w * w1.w; asm volatile("" : "+v"(t)); a7 = a7 + t;
    }
  }
  float xs2 = ((a0 + a1) + (a2 + a3)) + ((a4 + a5) + (a6 + a7));

  int c = (int)cntg[r];
  if (c <= CAP) {
    float best = 3.4e38f;
    int bidx = 0x7fffffff;
    for (int j = 0; j < c; ++j) {
      int col = listsg[(size_t)r * CAP + j];
      float dot = 0.f;
      const float4* ev = (const float4*)(emb + (size_t)col * D_DIM);
#pragma unroll 8
      for (int d4 = 0; d4 < 32; ++d4) {  // exact ascending-d fmaf chain
        float4 e4 = ev[d4];
        dot = __builtin_fmaf(xr[d4 * 4 + 0], e4.x, dot);
        dot = __builtin_fmaf(xr[d4 * 4 + 1], e4.y, dot);
        dot = __builtin_fmaf(xr[d4 * 4 + 2], e4.z, dot);
        dot = __builtin_fmaf(xr[d4 * 4 + 3], e4.w, dot);
      }
      float t1 = xs2 + e2g[col];                 // fl(x2+e2)
      float s = __builtin_fmaf(-2.0f, dot, t1);  // fl(t1 - 2*dot)
      if (s < best || (s == best && col < bidx)) { best = s; bidx = col; }
    }
    out_idx[r] = (float)bidx;
    atomicAdd(&counts[bidx], 1u);
  } else {
    int p = atomicAdd(&nofl, 1);
    oflrows[p] = r;
  }
  __syncthreads();

  // cooperative exact full scan for overflow rows (expected never)
  for (int k = 0; k < nofl; ++k) {
    int rr = oflrows[k];
    const float* xrr = x + (size_t)rr * D_DIM;
    // recompute xs2 for rr (same exact recipe)
    float b0, b1, b2, b3, b4, b5, b6, b7;
    float4 v0 = ((const float4*)xrr)[0], v1 = ((const float4*)xrr)[1];
    float t;
    t = v0.x * v0.x; asm volatile("" : "+v"(t)); b0 = t;
    t = v0.y * v0.y; asm volatile("" : "+v"(t)); b1 = t;
    t = v0.z * v0.z; asm volatile("" : "+v"(t)); b2 = t;
    t = v0.w * v0.w; asm volatile("" : "+v"(t)); b3 = t;
    t = v1.x * v1.x; asm volatile("" : "+v"(t)); b4 = t;
    t = v1.y * v1.y; asm volatile("" : "+v"(t)); b5 = t;
    t = v1.z * v1.z; asm volatile("" : "+v"(t)); b6 = t;
    t = v1.w * v1.w; asm volatile("" : "+v"(t)); b7 = t;
#pragma unroll
    for (int i = 1; i < 16; ++i) {
      float4 w0 = ((const float4*)xrr)[i * 2], w1 = ((const float4*)xrr)[i * 2 + 1];
      t = w0.x * w0.x; asm volatile("" : "+v"(t)); b0 = b0 + t;
      t = w0.y * w0.y; asm volatile("" : "+v"(t)); b1 = b1 + t;
      t = w0.z * w0.z; asm volatile("" : "+v"(t)); b2 = b2 + t;
      t = w0.w * w0.w; asm volatile("" : "+v"(t)); b3 = b3 + t;
      t = w1.x * w1.x; asm volatile("" : "+v"(t)); b4 = b4 + t;
      t = w1.y * w1.y; asm volatile("" : "+v"(t)); b5 = b5 + t;
      t = w1.z * w1.z; asm volatile("" : "+v"(t)); b6 = b6 + t;
      t = w1.w * w1.w; asm volatile("" : "+v"(t)); b7 = b7 + t;
    }
    float xs2r = ((b0 + b1) + (b2 + b3)) + ((b4 + b5) + (b6 + b7));
    float lbest = 3.4e38f;
    int lidx = 0x7fffffff;
    for (int c0 = tid; c0 < K_CODES; c0 += 128) {
      float dot = 0.f;
      const float4* ev = (const float4*)(emb + (size_t)c0 * D_DIM);
      for (int d4 = 0; d4 < 32; ++d4) {
        float4 e4 = ev[d4];
        dot = __builtin_fmaf(xrr[d4 * 4 + 0], e4.x, dot);
        dot = __builtin_fmaf(xrr[d4 * 4 + 1], e4.y, dot);
        dot = __builtin_fmaf(xrr[d4 * 4 + 2], e4.z, dot);
        dot = __builtin_fmaf(xrr[d4 * 4 + 3], e4.w, dot);
      }
      float s = __builtin_fmaf(-2.0f, dot, xs2r + e2g[c0]);
      if (s < lbest || (s == lbest && c0 < lidx)) { lbest = s; lidx = c0; }
    }
    redv[tid] = lbest;
    redi[tid] = lidx;
    __syncthreads();
    if (tid == 0) {
      float bv = redv[0]; int bi = redi[0];
      for (int t2 = 1; t2 < 128; ++t2) {
        float v = redv[t2]; int i2 = redi[t2];
        if (v < bv || (v == bv && i2 < bi)) { bv = v; bi = i2; }
      }
      out_idx[rr] = (float)bi;
      atomicAdd(&counts[bi], 1u);
    }
    __syncthreads();
  }
}

// ---------------------------------------------------------------------------
// Kernel 5 (round-2..5 validated): gather + straight-through + losses.
// ---------------------------------------------------------------------------
__global__ __launch_bounds__(256) void vq_gather(const float* __restrict__ x,
                                                 const float* __restrict__ emb,
                                                 const float* __restrict__ idxf,
                                                 float* __restrict__ out_q,
                                                 double* __restrict__ sums) {
  int r = blockIdx.x * 8 + (threadIdx.x >> 5);
  int lane = threadIdx.x & 31;
  int idx = (int)idxf[r];
  const float4 q = *(const float4*)(emb + (size_t)idx * 128 + lane * 4);
  const float4 xv = *(const float4*)(x + (size_t)r * 128 + lane * 4);
  float d0 = q.x - xv.x, d1 = q.y - xv.y, d2 = q.z - xv.z, d3 = q.w - xv.w;
  float s0 = xv.x + d0, s1 = xv.y + d1, s2 = xv.z + d2, s3 = xv.w + d3;
  *(float4*)(out_q + (size_t)r * 128 + lane * 4) = make_float4(s0, s1, s2, s3);
  float g0 = s0 - xv.x, g1 = s1 - xv.y, g2 = s2 - xv.z, g3 = s3 - xv.w;
  double es = (double)(d0 * d0) + (double)(d1 * d1) + (double)(d2 * d2) + (double)(d3 * d3);
  double qs = (double)(g0 * g0) + (double)(g1 * g1) + (double)(g2 * g2) + (double)(g3 * g3);
#pragma unroll
  for (int off = 32; off >= 1; off >>= 1) {
    es += __shfl_down(es, off, 64);
    qs += __shfl_down(qs, off, 64);
  }
  __shared__ double lred[2][4];
  int w = threadIdx.x >> 6;
  if ((threadIdx.x & 63) == 0) { lred[0][w] = es; lred[1][w] = qs; }
  __syncthreads();
  if (threadIdx.x == 0) {
    double e = lred[0][0] + lred[0][1] + lred[0][2] + lred[0][3];
    double qq = lred[1][0] + lred[1][1] + lred[1][2] + lred[1][3];
    atomicAdd(&sums[0], e);
    atomicAdd(&sums[1], qq);
  }
}

// ---------------------------------------------------------------------------
// Kernel 6 (validated): finalize scalars.
// ---------------------------------------------------------------------------
__global__ __launch_bounds__(256) void vq_final(const unsigned int* __restrict__ counts,
                                                const double* __restrict__ sums,
                                                float* __restrict__ out_scalars) {
  double s = 0.0;
  for (int k = threadIdx.x; k < K_CODES; k += 256) {
    float p = (float)counts[k] * (1.0f / 32768.0f);
    float term = p * logf(p + 1e-10f);
    s += (double)term;
  }
#pragma unroll
  for (int off = 32; off >= 1; off >>= 1) s += __shfl_down(s, off, 64);
  __shared__ double red[4];
  if ((threadIdx.x & 63) == 0) red[threadIdx.x >> 6] = s;
  __syncthreads();
  if (threadIdx.x == 0) {
    double tot = red[0] + red[1] + red[2] + red[3];
    float e_lat = (float)(sums[0] / (double)(B_ROWS * D_DIM));
    float q_lat = (float)(sums[1] / (double)(B_ROWS * D_DIM));
    float vq = q_lat + 0.25f * e_lat;   // fl(q + fl(0.25*e)); 0.25*e exact
    out_scalars[0] = vq;
    out_scalars[1] = e_lat;
    out_scalars[2] = q_lat;
    out_scalars[3] = expf(-(float)tot);
  }
}

extern "C" void kernel_launch(void* const* d_in, const int* in_sizes, int n_in,
                              void* d_out, int out_size, void* d_ws, size_t ws_size,
                              hipStream_t stream) {
  const float* x = (const float*)d_in[0];
  const float* emb = (const float*)d_in[1];
  float* out = (float*)d_out;

  // ws (<300 KB): counts u32[4096] @0 | sums f64[2] @16384 | e2 @16400 |
  //               RMMg u32[32768] @32784 | cntg u32[32768] @163856
  unsigned int* counts = (unsigned int*)d_ws;
  double* sums = (double*)((char*)d_ws + 16384);
  float* e2 = (float*)((char*)d_ws + 16400);
  unsigned int* RMMg = (unsigned int*)((char*)d_ws + 32784);
  unsigned int* cntg = (unsigned int*)((char*)d_ws + 163856);

  // scratch in d_out's quantized region (consumed before vq_gather overwrites):
  // eb u16[524288] @out+0 (1 MB) | lists u16[32768*CAP] @out+1 MB (1.5 MB)
  unsigned short* eb = (unsigned short*)out;
  unsigned short* listsg = (unsigned short*)((char*)out + 1048576);

  float* out_idx = out + (size_t)B_ROWS * D_DIM;
  float* out_scalars = out_idx + B_ROWS;

  hipMemsetAsync(d_ws, 0, 16400, stream);  // zero counts + sums
  prep<<<128, 256, 0, stream>>>(emb, e2, eb);
  minpass<<<B_ROWS / 32, 256, 0, stream>>>(x, eb, e2, RMMg);
  collect<<<B_ROWS / 32, 256, 0, stream>>>(x, eb, e2, RMMg, cntg, listsg);
  rescore<<<B_ROWS / 128, 128, 0, stream>>>(x, emb, e2, cntg, listsg, out_idx, counts);
  vq_gather<<<B_ROWS / 8, 256, 0, stream>>>(x, emb, out_idx, out, sums);
  vq_final<<<1, 256, 0, stream>>>(counts, sums, out_scalars);
}

// Round 8
// 492.534 us; speedup vs baseline: 3.6211x; 1.0801x over previous
//
#include <hip/hip_runtime.h>
#include <math.h>

#define B_ROWS 32768
#define K_CODES 4096
#define D_DIM 128
#define MARGIN 1.5e-3f
#define CAP 24

typedef short bf16x8 __attribute__((ext_vector_type(8)));
typedef float f32x4 __attribute__((ext_vector_type(4)));

// RNE float->bf16 (finite inputs only)
__device__ __forceinline__ unsigned short f2bf(float f) {
  union { float f; unsigned int u; } v; v.f = f;
  unsigned int r = (v.u + 0x7FFFu + ((v.u >> 16) & 1u)) >> 16;
  return (unsigned short)r;
}

// order-preserving float<->uint mapping
__device__ __forceinline__ unsigned fmap(float f) {
  unsigned u = __float_as_uint(f);
  return (u & 0x80000000u) ? ~u : (u | 0x80000000u);
}
__device__ __forceinline__ float funmap(unsigned k) {
  unsigned u = (k & 0x80000000u) ? (k ^ 0x80000000u) : ~k;
  return __uint_as_float(u);
}

// ---------------------------------------------------------------------------
// Kernel 1: prep — e2 (validated numpy pairwise order) + eb cast packed in
// MFMA-fragment order: eb[((ch*8+nt)*4+ks)*64 + lane]*8 shorts, so a wave's
// B-fragment load is one fully-coalesced lane-contiguous dwordx4 (1 KB/instr).
// ---------------------------------------------------------------------------
__global__ __launch_bounds__(256) void prep(const float* __restrict__ emb,
                                            float* __restrict__ e2,
                                            unsigned short* __restrict__ eb) {
  const int t0 = blockIdx.x * 256 + threadIdx.x;
  const int stride = gridDim.x * 256;
  // (a) e2: 8 lanes/row, accumulator j sums fl(e_{8i+j}^2) i ascending, then
  // shfl-xor 1,2,4 == ((r0+r1)+(r2+r3))+((r4+r5)+(r6+r7)).
  for (int s = t0; s < K_CODES * 8; s += stride) {
    int row = s >> 3, lane = s & 7;
    const float* src = emb + (size_t)row * D_DIM;
    float v = src[lane];
    float t = v * v;
    asm volatile("" : "+v"(t));  // keep fl(v*v) un-fused
    float acc = t;
#pragma unroll
    for (int i = 1; i < 16; ++i) {
      float w = src[i * 8 + lane];
      float tt = w * w;
      asm volatile("" : "+v"(tt));
      acc = acc + tt;
    }
    acc = acc + __shfl_xor(acc, 1, 64);
    acc = acc + __shfl_xor(acc, 2, 64);
    acc = acc + __shfl_xor(acc, 4, 64);
    if (lane == 0) e2[row] = acc;
  }
  // (b) packed bf16 cast: work item = (code c, ks)
  for (int g = t0; g < K_CODES * 4; g += stride) {
    int c = g >> 2, ks = g & 3;
    int ch = c >> 7, nt = (c >> 4) & 7, lr = c & 15;
    const float4* src = (const float4*)(emb + (size_t)c * D_DIM + ks * 32);
    unsigned short* dst = eb + ((size_t)((ch * 8 + nt) * 4 + ks) * 64 + lr) * 8;
#pragma unroll
    for (int qq = 0; qq < 4; ++qq) {
      float4 v0 = src[qq * 2];
      float4 v1 = src[qq * 2 + 1];
      ushort4 o0 = make_ushort4(f2bf(v0.x), f2bf(v0.y), f2bf(v0.z), f2bf(v0.w));
      ushort4 o1 = make_ushort4(f2bf(v1.x), f2bf(v1.y), f2bf(v1.z), f2bf(v1.w));
      *(ushort4*)(dst + qq * 128) = o0;
      *(ushort4*)(dst + qq * 128 + 4) = o1;
    }
  }
}

// ---------------------------------------------------------------------------
// Kernel 2 (round-7 validated): minpass — pure MFMA bf16 min.  256 thr
// (4 waves), 32 rows/block, 1024 blocks.  Wave wid covers n-tiles wid*2,
// wid*2+1; all waves cover m-tiles 0..1.  Rows block-exclusive -> plain store.
// ---------------------------------------------------------------------------
__global__ __launch_bounds__(256, 4) void minpass(
    const float* __restrict__ x, const unsigned short* __restrict__ eb,
    const float* __restrict__ e2g, unsigned int* __restrict__ RMMg) {
  __shared__ float m2[32 * 4];
  const int tid = threadIdx.x;
  const int wid = tid >> 6, lane = tid & 63;
  const int q = lane >> 4, lr = lane & 15;
  const int rowbase = blockIdx.x * 32;

  bf16x8 af[2][4];
#pragma unroll
  for (int mi = 0; mi < 2; ++mi) {
    const float* xr = x + (size_t)(rowbase + mi * 16 + lr) * D_DIM;
#pragma unroll
    for (int ks = 0; ks < 4; ++ks) {
      float4 v0 = *(const float4*)(xr + ks * 32 + q * 8);
      float4 v1 = *(const float4*)(xr + ks * 32 + q * 8 + 4);
      bf16x8 f;
      f[0] = (short)f2bf(v0.x); f[1] = (short)f2bf(v0.y);
      f[2] = (short)f2bf(v0.z); f[3] = (short)f2bf(v0.w);
      f[4] = (short)f2bf(v1.x); f[5] = (short)f2bf(v1.y);
      f[6] = (short)f2bf(v1.z); f[7] = (short)f2bf(v1.w);
      af[mi][ks] = f;
    }
  }

  float rm[8];
#pragma unroll
  for (int sl = 0; sl < 8; ++sl) rm[sl] = 3.4e38f;

#pragma unroll 2
  for (int ch = 0; ch < 32; ++ch) {
    bf16x8 bf[2][4];
    float ev[2];
#pragma unroll
    for (int ni = 0; ni < 2; ++ni) {
      int nt = wid * 2 + ni;
#pragma unroll
      for (int ks = 0; ks < 4; ++ks)
        bf[ni][ks] = *(const bf16x8*)(eb + ((size_t)((ch * 8 + nt) * 4 + ks) * 64 + lane) * 8);
      ev[ni] = e2g[ch * 128 + nt * 16 + lr];
    }
    f32x4 acc[2][2];
#pragma unroll
    for (int mi = 0; mi < 2; ++mi)
#pragma unroll
      for (int ni = 0; ni < 2; ++ni) { f32x4 z = {0.f, 0.f, 0.f, 0.f}; acc[mi][ni] = z; }
#pragma unroll
    for (int ks = 0; ks < 4; ++ks)
#pragma unroll
      for (int mi = 0; mi < 2; ++mi)
#pragma unroll
        for (int ni = 0; ni < 2; ++ni)
          acc[mi][ni] = __builtin_amdgcn_mfma_f32_16x16x32_bf16(
              af[mi][ks], bf[ni][ks], acc[mi][ni], 0, 0, 0);
#pragma unroll
    for (int mi = 0; mi < 2; ++mi)
#pragma unroll
      for (int ni = 0; ni < 2; ++ni)
#pragma unroll
        for (int rg = 0; rg < 4; ++rg) {
          float t = __builtin_fmaf(-2.0f, acc[mi][ni][rg], ev[ni]);
          rm[mi * 4 + rg] = fminf(rm[mi * 4 + rg], t);
        }
  }

#pragma unroll
  for (int sl = 0; sl < 8; ++sl) {
    float v = rm[sl];
    v = fminf(v, __shfl_xor(v, 1, 64));
    v = fminf(v, __shfl_xor(v, 2, 64));
    v = fminf(v, __shfl_xor(v, 4, 64));
    v = fminf(v, __shfl_xor(v, 8, 64));
    if (lr == 0) m2[((sl >> 2) * 16 + q * 4 + (sl & 3)) * 4 + wid] = v;
  }
  __syncthreads();
  if (tid < 32) {
    float a = fminf(m2[tid * 4], m2[tid * 4 + 1]);
    float b = fminf(m2[tid * 4 + 2], m2[tid * 4 + 3]);
    RMMg[rowbase + tid] = fmap(fminf(a, b));  // row is block-exclusive
  }
}

// ---------------------------------------------------------------------------
// Kernel 3 (round-7 validated): collect — recompute bf16 scores, append cols
// with t <= min+M.  Tight bound (exact global bf16 min) -> ~6/row.
// ---------------------------------------------------------------------------
__global__ __launch_bounds__(256, 4) void collect(
    const float* __restrict__ x, const unsigned short* __restrict__ eb,
    const float* __restrict__ e2g, const unsigned int* __restrict__ RMMg,
    unsigned int* __restrict__ cntg, unsigned short* __restrict__ listsg) {
  __shared__ float mlim[32];
  __shared__ unsigned cnt[32];
  __shared__ unsigned short lists[32 * CAP];
  const int tid = threadIdx.x;
  const int wid = tid >> 6, lane = tid & 63;
  const int q = lane >> 4, lr = lane & 15;
  const int rowbase = blockIdx.x * 32;

  if (tid < 32) {
    mlim[tid] = funmap(RMMg[rowbase + tid]) + MARGIN;
    cnt[tid] = 0;
  }

  bf16x8 af[2][4];
#pragma unroll
  for (int mi = 0; mi < 2; ++mi) {
    const float* xr = x + (size_t)(rowbase + mi * 16 + lr) * D_DIM;
#pragma unroll
    for (int ks = 0; ks < 4; ++ks) {
      float4 v0 = *(const float4*)(xr + ks * 32 + q * 8);
      float4 v1 = *(const float4*)(xr + ks * 32 + q * 8 + 4);
      bf16x8 f;
      f[0] = (short)f2bf(v0.x); f[1] = (short)f2bf(v0.y);
      f[2] = (short)f2bf(v0.z); f[3] = (short)f2bf(v0.w);
      f[4] = (short)f2bf(v1.x); f[5] = (short)f2bf(v1.y);
      f[6] = (short)f2bf(v1.z); f[7] = (short)f2bf(v1.w);
      af[mi][ks] = f;
    }
  }
  __syncthreads();
  float ml[8];
#pragma unroll
  for (int mi = 0; mi < 2; ++mi)
#pragma unroll
    for (int rg = 0; rg < 4; ++rg) ml[mi * 4 + rg] = mlim[mi * 16 + q * 4 + rg];

#pragma unroll 2
  for (int ch = 0; ch < 32; ++ch) {
    bf16x8 bf[2][4];
    float ev[2];
#pragma unroll
    for (int ni = 0; ni < 2; ++ni) {
      int nt = wid * 2 + ni;
#pragma unroll
      for (int ks = 0; ks < 4; ++ks)
        bf[ni][ks] = *(const bf16x8*)(eb + ((size_t)((ch * 8 + nt) * 4 + ks) * 64 + lane) * 8);
      ev[ni] = e2g[ch * 128 + nt * 16 + lr];
    }
    f32x4 acc[2][2];
#pragma unroll
    for (int mi = 0; mi < 2; ++mi)
#pragma unroll
      for (int ni = 0; ni < 2; ++ni) { f32x4 z = {0.f, 0.f, 0.f, 0.f}; acc[mi][ni] = z; }
#pragma unroll
    for (int ks = 0; ks < 4; ++ks)
#pragma unroll
      for (int mi = 0; mi < 2; ++mi)
#pragma unroll
        for (int ni = 0; ni < 2; ++ni)
          acc[mi][ni] = __builtin_amdgcn_mfma_f32_16x16x32_bf16(
              af[mi][ks], bf[ni][ks], acc[mi][ni], 0, 0, 0);
#pragma unroll
    for (int mi = 0; mi < 2; ++mi)
#pragma unroll
      for (int ni = 0; ni < 2; ++ni) {
        int colc = ch * 128 + (wid * 2 + ni) * 16 + lr;
#pragma unroll
        for (int rg = 0; rg < 4; ++rg) {
          float t = __builtin_fmaf(-2.0f, acc[mi][ni][rg], ev[ni]);
          if (t <= ml[mi * 4 + rg]) {
            int row = mi * 16 + q * 4 + rg;
            unsigned p = atomicAdd(&cnt[row], 1u);
            if (p < CAP) lists[row * CAP + p] = (unsigned short)colc;
          }
        }
      }
  }
  __syncthreads();
  if (tid < 32) cntg[rowbase + tid] = cnt[tid];
  for (int i = tid; i < 32 * CAP; i += 256)
    listsg[(size_t)rowbase * CAP + i] = lists[i];
}

// ---------------------------------------------------------------------------
// Kernel 4: rescore v2 — 8 lanes per row, 32 rows/block, 1024 blocks
// (16 waves/CU).  xs2 via the validated 8-lane numpy-pairwise pattern;
// candidates strided across lanes, each lane runs the exact serial
// ascending-d fmaf chain; lexicographic (s,col) shfl reduction preserves
// first-index tie-break.  Overflow rows (expected never): cooperative scan.
// ---------------------------------------------------------------------------
__global__ __launch_bounds__(256) void rescore(
    const float* __restrict__ x, const float* __restrict__ emb,
    const float* __restrict__ e2g, const unsigned int* __restrict__ cntg,
    const unsigned short* __restrict__ listsg, float* __restrict__ out_idx,
    unsigned int* __restrict__ counts) {
  __shared__ int nofl;
  __shared__ int oflrows[32];
  __shared__ float redv[256];
  __shared__ int redi[256];
  const int tid = threadIdx.x;
  const int rl = tid >> 3;   // row within block (0..31)
  const int j = tid & 7;     // lane within row-group
  const int r = blockIdx.x * 32 + rl;
  if (tid == 0) nofl = 0;
  __syncthreads();

  const float* xr = x + (size_t)r * D_DIM;
  // xs2: validated 8-lane numpy pairwise pattern (xor 1,2,4 stays in-group)
  float v = xr[j];
  float t = v * v;
  asm volatile("" : "+v"(t));  // keep fl(v*v) un-fused
  float acc = t;
#pragma unroll
  for (int i = 1; i < 16; ++i) {
    float w = xr[i * 8 + j];
    float tt = w * w;
    asm volatile("" : "+v"(tt));
    acc = acc + tt;
  }
  acc = acc + __shfl_xor(acc, 1, 64);
  acc = acc + __shfl_xor(acc, 2, 64);
  acc = acc + __shfl_xor(acc, 4, 64);
  const float xs2 = acc;  // all 8 lanes hold the row sum

  int c = (int)cntg[r];
  if (c <= CAP) {
    float best = 3.4e38f;
    int bidx = 0x7fffffff;
    for (int jj = j; jj < c; jj += 8) {
      int col = listsg[(size_t)r * CAP + jj];
      float dot = 0.f;
      const float4* ev = (const float4*)(emb + (size_t)col * D_DIM);
#pragma unroll 8
      for (int d4 = 0; d4 < 32; ++d4) {  // exact ascending-d fmaf chain
        float4 e4 = ev[d4];
        dot = __builtin_fmaf(xr[d4 * 4 + 0], e4.x, dot);
        dot = __builtin_fmaf(xr[d4 * 4 + 1], e4.y, dot);
        dot = __builtin_fmaf(xr[d4 * 4 + 2], e4.z, dot);
        dot = __builtin_fmaf(xr[d4 * 4 + 3], e4.w, dot);
      }
      float t1 = xs2 + e2g[col];                 // fl(x2+e2)
      float s = __builtin_fmaf(-2.0f, dot, t1);  // fl(t1 - 2*dot)
      if (s < best || (s == best && col < bidx)) { best = s; bidx = col; }
    }
    // lexicographic (s, col) min across the 8 lanes
#pragma unroll
    for (int m = 1; m <= 4; m <<= 1) {
      float ov = __shfl_xor(best, m, 64);
      int oi = __shfl_xor(bidx, m, 64);
      if (ov < best || (ov == best && oi < bidx)) { best = ov; bidx = oi; }
    }
    if (j == 0) {
      out_idx[r] = (float)bidx;
      atomicAdd(&counts[bidx], 1u);
    }
  } else if (j == 0) {
    int p = atomicAdd(&nofl, 1);
    oflrows[p] = r;
  }
  __syncthreads();

  // cooperative exact full scan for overflow rows (expected never)
  for (int k = 0; k < nofl; ++k) {
    int rr = oflrows[k];
    const float* xrr = x + (size_t)rr * D_DIM;
    float b0, b1, b2, b3, b4, b5, b6, b7;
    float4 v0 = ((const float4*)xrr)[0], v1 = ((const float4*)xrr)[1];
    float tx;
    tx = v0.x * v0.x; asm volatile("" : "+v"(tx)); b0 = tx;
    tx = v0.y * v0.y; asm volatile("" : "+v"(tx)); b1 = tx;
    tx = v0.z * v0.z; asm volatile("" : "+v"(tx)); b2 = tx;
    tx = v0.w * v0.w; asm volatile("" : "+v"(tx)); b3 = tx;
    tx = v1.x * v1.x; asm volatile("" : "+v"(tx)); b4 = tx;
    tx = v1.y * v1.y; asm volatile("" : "+v"(tx)); b5 = tx;
    tx = v1.z * v1.z; asm volatile("" : "+v"(tx)); b6 = tx;
    tx = v1.w * v1.w; asm volatile("" : "+v"(tx)); b7 = tx;
#pragma unroll
    for (int i = 1; i < 16; ++i) {
      float4 w0 = ((const float4*)xrr)[i * 2], w1 = ((const float4*)xrr)[i * 2 + 1];
      tx = w0.x * w0.x; asm volatile("" : "+v"(tx)); b0 = b0 + tx;
      tx = w0.y * w0.y; asm volatile("" : "+v"(tx)); b1 = b1 + tx;
      tx = w0.z * w0.z; asm volatile("" : "+v"(tx)); b2 = b2 + tx;
      tx = w0.w * w0.w; asm volatile("" : "+v"(tx)); b3 = b3 + tx;
      tx = w1.x * w1.x; asm volatile("" : "+v"(tx)); b4 = b4 + tx;
      tx = w1.y * w1.y; asm volatile("" : "+v"(tx)); b5 = b5 + tx;
      tx = w1.z * w1.z; asm volatile("" : "+v"(tx)); b6 = b6 + tx;
      tx = w1.w * w1.w; asm volatile("" : "+v"(tx)); b7 = b7 + tx;
    }
    float xs2r = ((b0 + b1) + (b2 + b3)) + ((b4 + b5) + (b6 + b7));
    float lbest = 3.4e38f;
    int lidx = 0x7fffffff;
    for (int c0 = tid; c0 < K_CODES; c0 += 256) {
      float dot = 0.f;
      const float4* ev = (const float4*)(emb + (size_t)c0 * D_DIM);
      for (int d4 = 0; d4 < 32; ++d4) {
        float4 e4 = ev[d4];
        dot = __builtin_fmaf(xrr[d4 * 4 + 0], e4.x, dot);
        dot = __builtin_fmaf(xrr[d4 * 4 + 1], e4.y, dot);
        dot = __builtin_fmaf(xrr[d4 * 4 + 2], e4.z, dot);
        dot = __builtin_fmaf(xrr[d4 * 4 + 3], e4.w, dot);
      }
      float s = __builtin_fmaf(-2.0f, dot, xs2r + e2g[c0]);
      if (s < lbest || (s == lbest && c0 < lidx)) { lbest = s; lidx = c0; }
    }
    redv[tid] = lbest;
    redi[tid] = lidx;
    __syncthreads();
    if (tid == 0) {
      float bv = redv[0]; int bi = redi[0];
      for (int t2 = 1; t2 < 256; ++t2) {
        float vv = redv[t2]; int i2 = redi[t2];
        if (vv < bv || (vv == bv && i2 < bi)) { bv = vv; bi = i2; }
      }
      out_idx[rr] = (float)bi;
      atomicAdd(&counts[bi], 1u);
    }
    __syncthreads();
  }
}

// ---------------------------------------------------------------------------
// Kernel 5 (round-2..7 validated): gather + straight-through + losses.
// ---------------------------------------------------------------------------
__global__ __launch_bounds__(256) void vq_gather(const float* __restrict__ x,
                                                 const float* __restrict__ emb,
                                                 const float* __restrict__ idxf,
                                                 float* __restrict__ out_q,
                                                 double* __restrict__ sums) {
  int r = blockIdx.x * 8 + (threadIdx.x >> 5);
  int lane = threadIdx.x & 31;
  int idx = (int)idxf[r];
  const float4 q = *(const float4*)(emb + (size_t)idx * 128 + lane * 4);
  const float4 xv = *(const float4*)(x + (size_t)r * 128 + lane * 4);
  float d0 = q.x - xv.x, d1 = q.y - xv.y, d2 = q.z - xv.z, d3 = q.w - xv.w;
  float s0 = xv.x + d0, s1 = xv.y + d1, s2 = xv.z + d2, s3 = xv.w + d3;
  *(float4*)(out_q + (size_t)r * 128 + lane * 4) = make_float4(s0, s1, s2, s3);
  float g0 = s0 - xv.x, g1 = s1 - xv.y, g2 = s2 - xv.z, g3 = s3 - xv.w;
  double es = (double)(d0 * d0) + (double)(d1 * d1) + (double)(d2 * d2) + (double)(d3 * d3);
  double qs = (double)(g0 * g0) + (double)(g1 * g1) + (double)(g2 * g2) + (double)(g3 * g3);
#pragma unroll
  for (int off = 32; off >= 1; off >>= 1) {
    es += __shfl_down(es, off, 64);
    qs += __shfl_down(qs, off, 64);
  }
  __shared__ double lred[2][4];
  int w = threadIdx.x >> 6;
  if ((threadIdx.x & 63) == 0) { lred[0][w] = es; lred[1][w] = qs; }
  __syncthreads();
  if (threadIdx.x == 0) {
    double e = lred[0][0] + lred[0][1] + lred[0][2] + lred[0][3];
    double qq = lred[1][0] + lred[1][1] + lred[1][2] + lred[1][3];
    atomicAdd(&sums[0], e);
    atomicAdd(&sums[1], qq);
  }
}

// ---------------------------------------------------------------------------
// Kernel 6 (validated): finalize scalars.
// ---------------------------------------------------------------------------
__global__ __launch_bounds__(256) void vq_final(const unsigned int* __restrict__ counts,
                                                const double* __restrict__ sums,
                                                float* __restrict__ out_scalars) {
  double s = 0.0;
  for (int k = threadIdx.x; k < K_CODES; k += 256) {
    float p = (float)counts[k] * (1.0f / 32768.0f);
    float term = p * logf(p + 1e-10f);
    s += (double)term;
  }
#pragma unroll
  for (int off = 32; off >= 1; off >>= 1) s += __shfl_down(s, off, 64);
  __shared__ double red[4];
  if ((threadIdx.x & 63) == 0) red[threadIdx.x >> 6] = s;
  __syncthreads();
  if (threadIdx.x == 0) {
    double tot = red[0] + red[1] + red[2] + red[3];
    float e_lat = (float)(sums[0] / (double)(B_ROWS * D_DIM));
    float q_lat = (float)(sums[1] / (double)(B_ROWS * D_DIM));
    float vq = q_lat + 0.25f * e_lat;   // fl(q + fl(0.25*e)); 0.25*e exact
    out_scalars[0] = vq;
    out_scalars[1] = e_lat;
    out_scalars[2] = q_lat;
    out_scalars[3] = expf(-(float)tot);
  }
}

extern "C" void kernel_launch(void* const* d_in, const int* in_sizes, int n_in,
                              void* d_out, int out_size, void* d_ws, size_t ws_size,
                              hipStream_t stream) {
  const float* x = (const float*)d_in[0];
  const float* emb = (const float*)d_in[1];
  float* out = (float*)d_out;

  // ws (<300 KB): counts u32[4096] @0 | sums f64[2] @16384 | e2 @16400 |
  //               RMMg u32[32768] @32784 | cntg u32[32768] @163856
  unsigned int* counts = (unsigned int*)d_ws;
  double* sums = (double*)((char*)d_ws + 16384);
  float* e2 = (float*)((char*)d_ws + 16400);
  unsigned int* RMMg = (unsigned int*)((char*)d_ws + 32784);
  unsigned int* cntg = (unsigned int*)((char*)d_ws + 163856);

  // scratch in d_out's quantized region (consumed before vq_gather overwrites):
  // eb u16[524288] @out+0 (1 MB) | lists u16[32768*CAP] @out+1 MB (1.5 MB)
  unsigned short* eb = (unsigned short*)out;
  unsigned short* listsg = (unsigned short*)((char*)out + 1048576);

  float* out_idx = out + (size_t)B_ROWS * D_DIM;
  float* out_scalars = out_idx + B_ROWS;

  hipMemsetAsync(d_ws, 0, 16400, stream);  // zero counts + sums
  prep<<<128, 256, 0, stream>>>(emb, e2, eb);
  minpass<<<B_ROWS / 32, 256, 0, stream>>>(x, eb, e2, RMMg);
  collect<<<B_ROWS / 32, 256, 0, stream>>>(x, eb, e2, RMMg, cntg, listsg);
  rescore<<<B_ROWS / 32, 256, 0, stream>>>(x, emb, e2, cntg, listsg, out_idx, counts);
  vq_gather<<<B_ROWS / 8, 256, 0, stream>>>(x, emb, out_idx, out, sums);
  vq_final<<<1, 256, 0, stream>>>(counts, sums, out_scalars);
}